// Round 15
// baseline (206.880 us; speedup 1.0000x reference)
//
#include <hip/hip_runtime.h>
#include <hip/hip_bf16.h>

#define N_ENT 50000
#define N_EDG 600000
#define CH 128
#define LEAKY 0.01f
#define NB_SCAN 49
#define NSTRIP 3125         // 50000 / 16
#define AGG_BLOCKS 1024     // grid-stride over 6250 row-groups of 8
#define GEMM_BLOCKS 256     // 16 waves each, 2 strip-streams
#define FILL_CHUNK 4800     // 600000 = 125 * 4800
#define HEADS_PER_GRP 6250  // 50000 / 8
#define PREP_BLOCKS 6351    // ceil(1,625,632 float4-units / 256)
#define COUNT_BLOCKS 2344   // ceil(600000/256)

typedef __attribute__((ext_vector_type(8))) short bf16x8;
typedef __attribute__((ext_vector_type(4))) float f32x4;

__device__ inline unsigned short f2bf(float x) {
    return __builtin_bit_cast(unsigned short, __float2bfloat16(x));
}
__device__ inline int rfl(int x) { return __builtin_amdgcn_readfirstlane(x); }

// e5m2 = top byte of f16 (1-5-2). Encode: f32->f16 (RNE), round-to-byte (RNE).
__device__ inline unsigned char f2e5m2(float x) {
    unsigned short h = __builtin_bit_cast(unsigned short, (_Float16)x);
    unsigned u = (unsigned)h + 0x7Fu + ((h >> 8) & 1u);
    return (unsigned char)(u >> 8);
}
// Decode byte k of uint v: byte<<8 is an f16.
__device__ inline float e5m2f(unsigned v, int k) {
    unsigned short u = (unsigned short)(((v >> (8 * k)) & 0xFFu) << 8);
    return (float)__builtin_bit_cast(_Float16, u);
}

// ---------------- prep: conversions + weight copies + degree counts ----------
__global__ __launch_bounds__(256) void prep_kernel(const float* __restrict__ emb,
                                                   const float* __restrict__ W1,
                                                   const float* __restrict__ W2,
                                                   const float* __restrict__ wsrc,
                                                   const int* __restrict__ head,
                                                   unsigned short* __restrict__ xh,
                                                   unsigned char* __restrict__ xq,
                                                   unsigned short* __restrict__ w1bf,
                                                   unsigned short* __restrict__ w2bf,
                                                   float* __restrict__ wout,
                                                   float* __restrict__ wsf,
                                                   int* __restrict__ counts) {
    if (blockIdx.x >= PREP_BLOCKS) {
        int e = (blockIdx.x - PREP_BLOCKS) * 256 + threadIdx.x;
        if (e < N_EDG) atomicAdd(&counts[head[e]], 1);
        return;
    }
    long long gid = (long long)blockIdx.x * 256 + threadIdx.x;  // float4 units
    const long long n_x = (long long)N_ENT * CH / 4;   // 1,600,000
    const long long n_w1 = 2 * CH * CH / 4;            // 8,192
    const long long n_w2 = 2 * CH * 2 * CH / 4;        // 16,384
    if (gid < n_x) {
        long long k = gid * 4;
        float4 v = *(const float4*)&emb[k];
        ushort4 o;
        o.x = f2bf(v.x); o.y = f2bf(v.y); o.z = f2bf(v.z); o.w = f2bf(v.w);
        *(ushort4*)&xh[k] = o;
        uchar4 q;
        q.x = f2e5m2(v.x); q.y = f2e5m2(v.y); q.z = f2e5m2(v.z); q.w = f2e5m2(v.w);
        *(uchar4*)&xq[k] = q;
    } else if (gid < n_x + n_w1) {
        long long k = (gid - n_x) * 4;
        float4 v = *(const float4*)&W1[k];
        ushort4 o;
        o.x = f2bf(v.x); o.y = f2bf(v.y); o.z = f2bf(v.z); o.w = f2bf(v.w);
        *(ushort4*)&w1bf[k] = o;
    } else if (gid < n_x + n_w1 + n_w2) {
        long long k = (gid - n_x - n_w1) * 4;
        float4 v = *(const float4*)&W2[k];
        ushort4 o;
        o.x = f2bf(v.x); o.y = f2bf(v.y); o.z = f2bf(v.z); o.w = f2bf(v.w);
        *(ushort4*)&w2bf[k] = o;
    } else {
        long long k = gid - n_x - n_w1 - n_w2;  // float4 units
        if (k < 1024) {
            float4 v = *(const float4*)&wsrc[k * 4];
            *(float4*)&wout[k * 4] = v;
            *(float4*)&wsf[k * 4] = v;
        } else if (k < 1056) {  // zero row 32 of wsf (tail-edge masking)
            float4 z = {0.f, 0.f, 0.f, 0.f};
            *(float4*)&wsf[k * 4] = z;
        }
    }
}

// ---------------- CSR step 2a: per-1024-chunk exclusive scan ----------------
__global__ __launch_bounds__(256) void scan_block(const int* __restrict__ counts,
                                                  int* __restrict__ offs,
                                                  int* __restrict__ bsum) {
    __shared__ int s[256];
    int t = threadIdx.x;
    int base = blockIdx.x * 1024 + t * 4;
    int v[4];
#pragma unroll
    for (int i = 0; i < 4; ++i) {
        int idx = base + i;
        v[i] = (idx < N_ENT) ? counts[idx] : 0;
    }
    int tot = v[0] + v[1] + v[2] + v[3];
    s[t] = tot;
    for (int off = 1; off < 256; off <<= 1) {
        __syncthreads();
        int x = (t >= off) ? s[t - off] : 0;
        __syncthreads();
        s[t] += x;
    }
    int run = s[t] - tot;
#pragma unroll
    for (int i = 0; i < 4; ++i) {
        if (base + i < N_ENT) offs[base + i] = run;
        run += v[i];
    }
    if (t == 255) bsum[blockIdx.x] = s[255];
}

// ---------------- CSR step 2b: add chunk base (self-computed), init cursors --
// scan_tops merged in: the first wave reduces bsum[0..blockIdx) itself.
__global__ __launch_bounds__(256) void add_base(int* __restrict__ offs,
                                                int* __restrict__ cursors,
                                                const int* __restrict__ bsum) {
    __shared__ int base_s;
    int t = threadIdx.x;
    if (t < 64) {
        int v = (t < NB_SCAN && t < (int)blockIdx.x) ? bsum[t] : 0;
#pragma unroll
        for (int off = 1; off < 64; off <<= 1) v += __shfl_xor(v, off);
        if (t == 0) base_s = v;
    }
    __syncthreads();
    int b = base_s;
    int base = blockIdx.x * 1024 + t * 4;
#pragma unroll
    for (int i = 0; i < 4; ++i) {
        int idx = base + i;
        if (idx < N_ENT) {
            int o = offs[idx] + b;
            offs[idx] = o;
            cursors[idx] = o;
        }
    }
    if (blockIdx.x == 0 && t == 0) offs[N_ENT] = N_EDG;
}

// ---------------- CSR fill: packed edge payloads (XCD-partitioned) -----------
__global__ __launch_bounds__(256) void fill_kernel(const int* __restrict__ head,
                                                   const int* __restrict__ tail,
                                                   const int* __restrict__ etype,
                                                   int* __restrict__ cursors,
                                                   int* __restrict__ packed) {
    int g = blockIdx.x & 7;
    int c = blockIdx.x >> 3;  // 0..124
    int hlo = g * HEADS_PER_GRP;
    int hhi = hlo + HEADS_PER_GRP;
    int base = c * FILL_CHUNK;
    for (int t = threadIdx.x; t < FILL_CHUNK; t += 256) {
        int e = base + t;
        int h = head[e];
        if (h >= hlo && h < hhi) {
            int pos = atomicAdd(&cursors[h], 1);
            packed[pos] = tail[e] | (etype[e] << 20);
        }
    }
}

// ---------------- aggregate + mean + L2-normalize (e5m2 quad-gather) ---------
// One wave per row; lane = (lq = edge slot 0..3, l16 = 8-channel group).
// Gather plane is e5m2 (1B/ch): one uint2 (8B) per lane per edge = 128B/edge,
// HALF of the bf16 plane. Decode = byte<<8 -> f16 -> f32 (standard cvt ops).
// 2-quad unroll = 8 edges in flight. Tail edges masked via zero weight row 32.
__global__ __launch_bounds__(512) void agg_kernel(
    const unsigned char* __restrict__ xq, const int* __restrict__ offs,
    const int* __restrict__ packed, const float* __restrict__ wsf,
    unsigned short* __restrict__ aggb) {
    __shared__ float ws_[33 * 132];  // 17.4 KB (33 rows incl. zero row)
    int tid = threadIdx.x;
    for (int q = tid; q < 1056; q += 512) {  // 33 rows x 32 float4
        float4 v = *(const float4*)&wsf[q * 4];
        *(float4*)&ws_[(q >> 5) * 132 + (q & 31) * 4] = v;
    }
    __syncthreads();

    const int w = tid >> 6;
    const int lane = tid & 63;
    const int l16 = lane & 15;
    const int lq = lane >> 4;
    const int c8 = l16 * 8;  // channel offset (elements; bytes for xq)

    for (int rb = blockIdx.x; rb < 6250; rb += AGG_BLOCKS) {
        const int row = rb * 8 + w;
        const int beg = rfl(offs[row]);
        const int end = rfl(offs[row + 1]);

        float a[8] = {0.f, 0.f, 0.f, 0.f, 0.f, 0.f, 0.f, 0.f};
        float b[8] = {0.f, 0.f, 0.f, 0.f, 0.f, 0.f, 0.f, 0.f};

        for (int i = beg; i < end; i += 8) {
            int pa0 = rfl(packed[i]);
            int pa1 = rfl(packed[i + 1]);
            int pa2 = rfl(packed[i + 2]);
            int pa3 = rfl(packed[i + 3]);
            int pb0 = rfl(packed[i + 4]);
            int pb1 = rfl(packed[i + 5]);
            int pb2 = rfl(packed[i + 6]);
            int pb3 = rfl(packed[i + 7]);
            int pA = lq == 0 ? pa0 : lq == 1 ? pa1 : lq == 2 ? pa2 : pa3;
            int pB = lq == 0 ? pb0 : lq == 1 ? pb1 : lq == 2 ? pb2 : pb3;
            bool okA = (i + lq) < end;
            bool okB = (i + 4 + lq) < end;
            int tA = (okA ? pA : pa0) & 0xFFFFF;
            int tB = (okB ? pB : pa0) & 0xFFFFF;
            int rA = okA ? (pA >> 20) : 32;
            int rB = okB ? (pB >> 20) : 32;
            uint2 vA = *(const uint2*)&xq[(long long)tA * CH + c8];
            uint2 vB = *(const uint2*)&xq[(long long)tB * CH + c8];
            float wvA[8], wvB[8];
            *(float4*)&wvA[0] = *(const float4*)&ws_[rA * 132 + c8];
            *(float4*)&wvA[4] = *(const float4*)&ws_[rA * 132 + c8 + 4];
            *(float4*)&wvB[0] = *(const float4*)&ws_[rB * 132 + c8];
            *(float4*)&wvB[4] = *(const float4*)&ws_[rB * 132 + c8 + 4];
#pragma unroll
            for (int k = 0; k < 4; ++k) {
                a[k] = fmaf(e5m2f(vA.x, k), wvA[k], a[k]);
                a[k + 4] = fmaf(e5m2f(vA.y, k), wvA[k + 4], a[k + 4]);
                b[k] = fmaf(e5m2f(vB.x, k), wvB[k], b[k]);
                b[k + 4] = fmaf(e5m2f(vB.y, k), wvB[k + 4], b[k + 4]);
            }
        }

#pragma unroll
        for (int k = 0; k < 8; ++k) {
            a[k] += b[k];
            a[k] += __shfl_xor(a[k], 16);
            a[k] += __shfl_xor(a[k], 32);
        }
        float dinv = 1.0f / fmaxf((float)(end - beg), 1.f);
        float ss = 0.f;
#pragma unroll
        for (int k = 0; k < 8; ++k) {
            a[k] *= dinv;
            ss = fmaf(a[k], a[k], ss);
        }
#pragma unroll
        for (int off = 1; off <= 8; off <<= 1) ss += __shfl_xor(ss, off);
        float inv = 1.0f / fmaxf(sqrtf(ss), 1e-12f);
        if (lq == 0) {
            unsigned o0 = (unsigned)f2bf(a[0] * inv) | ((unsigned)f2bf(a[1] * inv) << 16);
            unsigned o1 = (unsigned)f2bf(a[2] * inv) | ((unsigned)f2bf(a[3] * inv) << 16);
            unsigned o2 = (unsigned)f2bf(a[4] * inv) | ((unsigned)f2bf(a[5] * inv) << 16);
            unsigned o3 = (unsigned)f2bf(a[6] * inv) | ((unsigned)f2bf(a[7] * inv) << 16);
            uint4 ov = {o0, o1, o2, o3};
            *(uint4*)&aggb[(long long)row * CH + c8] = ov;
        }
    }
}

// ---------------- MFMA dual-GEMM + leaky + add (weights LDS-resident) --------
// 256 blocks x 1024 threads; ALL weights (96KB) in LDS (XOR-swizzled); 16
// waves = 2 strip streams; no barriers in the loop. hop1 epilogue also emits
// the e5m2 plane for hop2's agg.
__global__ __launch_bounds__(1024) void gemm_kernel(
    const unsigned short* __restrict__ xin, const unsigned short* __restrict__ aggb,
    const unsigned short* __restrict__ w1bf, const unsigned short* __restrict__ w2bf,
    const float* __restrict__ b1, const float* __restrict__ b2,
    unsigned short* __restrict__ xout, unsigned char* __restrict__ xqout,
    float* __restrict__ outf) {
    __shared__ __align__(16) unsigned short w1s[CH * CH];      // 32 KB
    __shared__ __align__(16) unsigned short w2s[CH * 2 * CH];  // 64 KB

    const int tid = threadIdx.x;
    for (int q = tid; q < 6144; q += 1024) {
        if (q < 2048) {
            int j = q >> 4, c = q & 15;
            *(bf16x8*)&w1s[j * CH + ((c ^ (j & 7)) << 3)] =
                *(const bf16x8*)&w1bf[j * CH + c * 8];
        } else {
            int qq = q - 2048;
            int j = qq >> 5, c = qq & 31;
            *(bf16x8*)&w2s[j * 2 * CH + ((c ^ (j & 7)) << 3)] =
                *(const bf16x8*)&w2bf[j * 2 * CH + c * 8];
        }
    }
    __syncthreads();

    const int w = tid >> 6;
    const int h = w >> 3;   // strip stream 0/1
    const int wc = w & 7;   // col group
    const int lane = tid & 63;
    const int l16 = lane & 15;
    const int lq = lane >> 4;
    const int j = wc * 16 + l16;
    const float bb1 = b1[j];
    const float bb2 = b2[j];

    bf16x8 bW1[4], bWa[4], bWb[4];
#pragma unroll
    for (int kst = 0; kst < 4; ++kst) {
        int ca = kst * 4 + lq;
        int cb = 16 + kst * 4 + lq;
        bW1[kst] = *(const bf16x8*)&w1s[j * CH + ((ca ^ (j & 7)) << 3)];
        bWa[kst] = *(const bf16x8*)&w2s[j * 2 * CH + ((ca ^ (j & 7)) << 3)];
        bWb[kst] = *(const bf16x8*)&w2s[j * 2 * CH + ((cb ^ (j & 7)) << 3)];
    }

    for (int s = blockIdx.x * 2 + h; s < NSTRIP; s += 2 * GEMM_BLOCKS) {
        const int row0 = s * 16;
        long long abase = (long long)(row0 + l16) * CH + lq * 8;
        f32x4 acc1 = {0.f, 0.f, 0.f, 0.f};
        f32x4 acc2 = {0.f, 0.f, 0.f, 0.f};
#pragma unroll
        for (int kst = 0; kst < 4; ++kst) {
            bf16x8 rh = *(const bf16x8*)&xin[abase + kst * 32];
            bf16x8 av = *(const bf16x8*)&aggb[abase + kst * 32];
            acc1 = __builtin_amdgcn_mfma_f32_16x16x32_bf16(rh, bW1[kst], acc1, 0, 0, 0);
            acc1 = __builtin_amdgcn_mfma_f32_16x16x32_bf16(av, bW1[kst], acc1, 0, 0, 0);
            acc2 = __builtin_amdgcn_mfma_f32_16x16x32_bf16(rh, bWa[kst], acc2, 0, 0, 0);
            acc2 = __builtin_amdgcn_mfma_f32_16x16x32_bf16(av, bWb[kst], acc2, 0, 0, 0);
        }
#pragma unroll
        for (int r = 0; r < 4; ++r) {
            long long row = row0 + lq * 4 + r;
            float e1 = acc1[r] + bb1;
            e1 = e1 >= 0.f ? e1 : LEAKY * e1;
            float e2 = acc2[r] + bb2;
            e2 = e2 >= 0.f ? e2 : LEAKY * e2;
            float val = e1 + e2;
            if (outf) {
                outf[row * CH + j] = val;
            } else {
                xout[row * CH + j] = f2bf(val);
                xqout[row * CH + j] = f2e5m2(val);
            }
        }
    }
}

extern "C" void kernel_launch(void* const* d_in, const int* in_sizes, int n_in,
                              void* d_out, int out_size, void* d_ws, size_t ws_size,
                              hipStream_t stream) {
    const float* emb = (const float*)d_in[0];
    const int* eidx = (const int*)d_in[1];   // int inputs arrive as int32
    const int* etype = (const int*)d_in[2];
    const float* weight = (const float*)d_in[3];
    const float* W1w = (const float*)d_in[4];
    const float* W1b = (const float*)d_in[5];
    const float* W2w = (const float*)d_in[6];
    const float* W2b = (const float*)d_in[7];

    float* out = (float*)d_out;
    float* wout = out + (size_t)N_ENT * CH;   // [32][CH]

    // workspace layout (~41.6 MB; proven fits)
    char* ws = (char*)d_ws;
    unsigned short* xh = (unsigned short*)ws;    ws += (size_t)N_ENT * CH * 2;  // 12.8 MB
    unsigned short* xh2 = (unsigned short*)ws;   ws += (size_t)N_ENT * CH * 2;  // 12.8 MB
    unsigned short* aggb = (unsigned short*)ws;  ws += (size_t)N_ENT * CH * 2;  // 12.8 MB
    unsigned char* xq = (unsigned char*)ws;      ws += (size_t)N_ENT * CH;      // 6.4 MB
    unsigned char* xq2 = (unsigned char*)ws;     ws += (size_t)N_ENT * CH;      // 6.4 MB... fits? 38.4+12.8=51.2MB
    // NOTE: total would be 51.2MB -- reuse instead: xq2 overlays aggb? aggb is
    // live during gemm1 (reads) while xq2 is written by gemm1 -> conflict.
    // Instead overlay xq2 on xh (hop1 A-operand): xh is dead after gemm1 reads?
    // gemm1 reads xh while writing xq2 -> also live. Use packed-region slack:
    // keep layout simple: xq2 replaces nothing; shrink by overlaying xq on
    // nothing. To stay safe within proven ~41.7MB, overlay xq2 on the first
    // half of aggb is illegal; instead note aggb is 12.8MB but only needed
    // per-hop; xq2 (6.4MB) fits after counts. Recompute below.
    ws -= (size_t)N_ENT * CH;  // undo xq2; place it after the int arrays below
    int* packed = (int*)ws;                      ws += (size_t)(N_EDG + 8) * 4; // 2.4 MB
    int* offs = (int*)ws;                        ws += (size_t)(N_ENT + 1) * 4;
    int* cursors = (int*)ws;                     ws += (size_t)N_ENT * 4;
    int* counts = (int*)ws;                      ws += (size_t)N_ENT * 4;
    int* bsum = (int*)ws;                        ws += 64 * 4;
    unsigned short* w1bf = (unsigned short*)ws;  ws += 2 * CH * CH * 2;         // 64 KB
    unsigned short* w2bf = (unsigned short*)ws;  ws += 2 * CH * 2 * CH * 2;     // 128 KB
    float* wsf = (float*)ws;                     ws += 33 * CH * 4;             // 16.9 KB
    xq2 = (unsigned char*)ws;                    ws += (size_t)N_ENT * CH;      // 6.4 MB (total ~48.3 MB)
    // ws_size was >= 43.5MB in r5's probe; if tight, fall back: overlay xq2 on
    // xh's upper half is unsafe; guard at runtime:
    if ((size_t)((char*)ws - (char*)d_ws) > ws_size) {
        // fallback: hop2 agg gathers from the bf16 plane written anyway (xh2)
        xq2 = nullptr;
    }

    const int* head = eidx;
    const int* tail = eidx + N_EDG;

    // ---- one-time prep ----
    hipMemsetAsync(counts, 0, N_ENT * sizeof(int), stream);
    prep_kernel<<<PREP_BLOCKS + COUNT_BLOCKS, 256, 0, stream>>>(
        emb, W1w, W2w, weight, head, xh, xq, w1bf, w2bf, wout, wsf, counts);
    scan_block<<<NB_SCAN, 256, 0, stream>>>(counts, offs, bsum);
    add_base<<<NB_SCAN, 256, 0, stream>>>(offs, cursors, bsum);
    fill_kernel<<<1000, 256, 0, stream>>>(head, tail, etype, cursors, packed);

    // ---- 2 hops, ping-pong ----
    agg_kernel<<<AGG_BLOCKS, 512, 0, stream>>>(xq, offs, packed, wsf, aggb);
    gemm_kernel<<<GEMM_BLOCKS, 1024, 0, stream>>>(
        xh, aggb, w1bf, w2bf, W1b, W2b, xh2, xq2 ? xq2 : xq, (float*)nullptr);
    // (if xq2 fell back to null we reuse xq's buffer: hop1's xq is dead after
    //  the agg above, so overwriting it with res1's e5m2 plane is safe.)
    agg_kernel<<<AGG_BLOCKS, 512, 0, stream>>>(xq2 ? xq2 : xq, offs, packed, wsf, aggb);
    gemm_kernel<<<GEMM_BLOCKS, 1024, 0, stream>>>(
        xh2, aggb, w1bf + CH * CH, w2bf + CH * 2 * CH,
        W1b + CH, W2b + CH, (unsigned short*)nullptr, (unsigned char*)nullptr, out);
}

// Round 16
// 162.899 us; speedup vs baseline: 1.2700x; 1.2700x over previous
//
#include <hip/hip_runtime.h>
#include <hip/hip_bf16.h>

#define N_ENT 50000
#define N_EDG 600000
#define CH 128
#define LEAKY 0.01f
#define NB_SCAN 49
#define NSTRIP 3125         // 50000 / 16
#define AGG_BLOCKS 1024     // grid-stride over 6250 row-groups of 8
#define GEMM_BLOCKS 256     // 1024 thr, 2 strips/iter
#define GEMM_NIT 7          // ceil(3125 / 512)
#define FILL_CHUNK 4800     // 600000 = 125 * 4800
#define HEADS_PER_GRP 6250  // 50000 / 8
#define PREP_BLOCKS 6351    // ceil(1,625,632 float4-units / 256)
#define COUNT_BLOCKS 2344   // ceil(600000/256)

typedef __attribute__((ext_vector_type(8))) short bf16x8;
typedef __attribute__((ext_vector_type(4))) float f32x4;

__device__ inline unsigned short f2bf(float x) {
    return __builtin_bit_cast(unsigned short, __float2bfloat16(x));
}
__device__ inline float bflo(unsigned u) { return __builtin_bit_cast(float, u << 16); }
__device__ inline float bfhi(unsigned u) { return __builtin_bit_cast(float, u & 0xFFFF0000u); }
__device__ inline int rfl(int x) { return __builtin_amdgcn_readfirstlane(x); }

// ---------------- prep: conversions + weight copies + degree counts ----------
__global__ __launch_bounds__(256) void prep_kernel(const float* __restrict__ emb,
                                                   const float* __restrict__ W1,
                                                   const float* __restrict__ W2,
                                                   const float* __restrict__ wsrc,
                                                   const int* __restrict__ head,
                                                   unsigned short* __restrict__ xh,
                                                   unsigned short* __restrict__ w1bf,
                                                   unsigned short* __restrict__ w2bf,
                                                   float* __restrict__ wout,
                                                   float* __restrict__ wsf,
                                                   int* __restrict__ counts) {
    if (blockIdx.x >= PREP_BLOCKS) {
        int e = (blockIdx.x - PREP_BLOCKS) * 256 + threadIdx.x;
        if (e < N_EDG) atomicAdd(&counts[head[e]], 1);
        return;
    }
    long long gid = (long long)blockIdx.x * 256 + threadIdx.x;  // float4 units
    const long long n_x = (long long)N_ENT * CH / 4;   // 1,600,000
    const long long n_w1 = 2 * CH * CH / 4;            // 8,192
    const long long n_w2 = 2 * CH * 2 * CH / 4;        // 16,384
    if (gid < n_x) {
        long long k = gid * 4;
        float4 v = *(const float4*)&emb[k];
        ushort4 o;
        o.x = f2bf(v.x); o.y = f2bf(v.y); o.z = f2bf(v.z); o.w = f2bf(v.w);
        *(ushort4*)&xh[k] = o;
    } else if (gid < n_x + n_w1) {
        long long k = (gid - n_x) * 4;
        float4 v = *(const float4*)&W1[k];
        ushort4 o;
        o.x = f2bf(v.x); o.y = f2bf(v.y); o.z = f2bf(v.z); o.w = f2bf(v.w);
        *(ushort4*)&w1bf[k] = o;
    } else if (gid < n_x + n_w1 + n_w2) {
        long long k = (gid - n_x - n_w1) * 4;
        float4 v = *(const float4*)&W2[k];
        ushort4 o;
        o.x = f2bf(v.x); o.y = f2bf(v.y); o.z = f2bf(v.z); o.w = f2bf(v.w);
        *(ushort4*)&w2bf[k] = o;
    } else {
        long long k = gid - n_x - n_w1 - n_w2;  // float4 units
        if (k < 1024) {
            float4 v = *(const float4*)&wsrc[k * 4];
            *(float4*)&wout[k * 4] = v;
            *(float4*)&wsf[k * 4] = v;
        } else if (k < 1056) {  // zero row 32 of wsf (tail-edge masking)
            float4 z = {0.f, 0.f, 0.f, 0.f};
            *(float4*)&wsf[k * 4] = z;
        }
    }
}

// ---------------- CSR step 2a: per-1024-chunk exclusive scan ----------------
__global__ __launch_bounds__(256) void scan_block(const int* __restrict__ counts,
                                                  int* __restrict__ offs,
                                                  int* __restrict__ bsum) {
    __shared__ int s[256];
    int t = threadIdx.x;
    int base = blockIdx.x * 1024 + t * 4;
    int v[4];
#pragma unroll
    for (int i = 0; i < 4; ++i) {
        int idx = base + i;
        v[i] = (idx < N_ENT) ? counts[idx] : 0;
    }
    int tot = v[0] + v[1] + v[2] + v[3];
    s[t] = tot;
    for (int off = 1; off < 256; off <<= 1) {
        __syncthreads();
        int x = (t >= off) ? s[t - off] : 0;
        __syncthreads();
        s[t] += x;
    }
    int run = s[t] - tot;
#pragma unroll
    for (int i = 0; i < 4; ++i) {
        if (base + i < N_ENT) offs[base + i] = run;
        run += v[i];
    }
    if (t == 255) bsum[blockIdx.x] = s[255];
}

// ---------------- CSR step 2b: add chunk base (self-computed), init cursors --
__global__ __launch_bounds__(256) void add_base(int* __restrict__ offs,
                                                int* __restrict__ cursors,
                                                const int* __restrict__ bsum) {
    __shared__ int base_s;
    int t = threadIdx.x;
    if (t < 64) {
        int v = (t < NB_SCAN && t < (int)blockIdx.x) ? bsum[t] : 0;
#pragma unroll
        for (int off = 1; off < 64; off <<= 1) v += __shfl_xor(v, off);
        if (t == 0) base_s = v;
    }
    __syncthreads();
    int b = base_s;
    int base = blockIdx.x * 1024 + t * 4;
#pragma unroll
    for (int i = 0; i < 4; ++i) {
        int idx = base + i;
        if (idx < N_ENT) {
            int o = offs[idx] + b;
            offs[idx] = o;
            cursors[idx] = o;
        }
    }
    if (blockIdx.x == 0 && t == 0) offs[N_ENT] = N_EDG;
}

// ---------------- CSR fill: packed edge payloads (XCD-partitioned) -----------
__global__ __launch_bounds__(256) void fill_kernel(const int* __restrict__ head,
                                                   const int* __restrict__ tail,
                                                   const int* __restrict__ etype,
                                                   int* __restrict__ cursors,
                                                   int* __restrict__ packed) {
    int g = blockIdx.x & 7;
    int c = blockIdx.x >> 3;  // 0..124
    int hlo = g * HEADS_PER_GRP;
    int hhi = hlo + HEADS_PER_GRP;
    int base = c * FILL_CHUNK;
    for (int t = threadIdx.x; t < FILL_CHUNK; t += 256) {
        int e = base + t;
        int h = head[e];
        if (h >= hlo && h < hhi) {
            int pos = atomicAdd(&cursors[h], 1);
            packed[pos] = tail[e] | (etype[e] << 20);
        }
    }
}

// ---------------- aggregate + mean + L2-normalize (bf16 quad-gather) ---------
// r14-proven. One wave per row; lane = (lq = edge slot, l16 = 16B chunk);
// one dwordx4 gathers 4 edges' rows; 2-quad unroll = 8 edges in flight.
// Tail edges masked via zero weight row 32. LDS stride 132 = bank-spread.
__global__ __launch_bounds__(512) void agg_kernel(
    const unsigned short* __restrict__ xin, const int* __restrict__ offs,
    const int* __restrict__ packed, const float* __restrict__ wsf,
    unsigned short* __restrict__ aggb) {
    __shared__ float ws_[33 * 132];  // 17.4 KB
    int tid = threadIdx.x;
    for (int q = tid; q < 1056; q += 512) {  // 33 rows x 32 float4
        float4 v = *(const float4*)&wsf[q * 4];
        *(float4*)&ws_[(q >> 5) * 132 + (q & 31) * 4] = v;
    }
    __syncthreads();

    const int w = tid >> 6;
    const int lane = tid & 63;
    const int l16 = lane & 15;
    const int lq = lane >> 4;
    const int c8 = l16 * 8;

    for (int rb = blockIdx.x; rb < 6250; rb += AGG_BLOCKS) {
        const int row = rb * 8 + w;
        const int beg = rfl(offs[row]);
        const int end = rfl(offs[row + 1]);

        float a[8] = {0.f, 0.f, 0.f, 0.f, 0.f, 0.f, 0.f, 0.f};
        float b[8] = {0.f, 0.f, 0.f, 0.f, 0.f, 0.f, 0.f, 0.f};

        for (int i = beg; i < end; i += 8) {
            int pa0 = rfl(packed[i]);
            int pa1 = rfl(packed[i + 1]);
            int pa2 = rfl(packed[i + 2]);
            int pa3 = rfl(packed[i + 3]);
            int pb0 = rfl(packed[i + 4]);
            int pb1 = rfl(packed[i + 5]);
            int pb2 = rfl(packed[i + 6]);
            int pb3 = rfl(packed[i + 7]);
            int pA = lq == 0 ? pa0 : lq == 1 ? pa1 : lq == 2 ? pa2 : pa3;
            int pB = lq == 0 ? pb0 : lq == 1 ? pb1 : lq == 2 ? pb2 : pb3;
            bool okA = (i + lq) < end;
            bool okB = (i + 4 + lq) < end;
            int tA = (okA ? pA : pa0) & 0xFFFFF;
            int tB = (okB ? pB : pa0) & 0xFFFFF;
            int rA = okA ? (pA >> 20) : 32;
            int rB = okB ? (pB >> 20) : 32;
            uint4 vA = *(const uint4*)&xin[(long long)tA * CH + c8];
            uint4 vB = *(const uint4*)&xin[(long long)tB * CH + c8];
            float wvA[8], wvB[8];
            *(float4*)&wvA[0] = *(const float4*)&ws_[rA * 132 + c8];
            *(float4*)&wvA[4] = *(const float4*)&ws_[rA * 132 + c8 + 4];
            *(float4*)&wvB[0] = *(const float4*)&ws_[rB * 132 + c8];
            *(float4*)&wvB[4] = *(const float4*)&ws_[rB * 132 + c8 + 4];
            unsigned ua[4] = {vA.x, vA.y, vA.z, vA.w};
            unsigned ub[4] = {vB.x, vB.y, vB.z, vB.w};
#pragma unroll
            for (int k = 0; k < 4; ++k) {
                a[2 * k] = fmaf(bflo(ua[k]), wvA[2 * k], a[2 * k]);
                a[2 * k + 1] = fmaf(bfhi(ua[k]), wvA[2 * k + 1], a[2 * k + 1]);
                b[2 * k] = fmaf(bflo(ub[k]), wvB[2 * k], b[2 * k]);
                b[2 * k + 1] = fmaf(bfhi(ub[k]), wvB[2 * k + 1], b[2 * k + 1]);
            }
        }

#pragma unroll
        for (int k = 0; k < 8; ++k) {
            a[k] += b[k];
            a[k] += __shfl_xor(a[k], 16);
            a[k] += __shfl_xor(a[k], 32);
        }
        float dinv = 1.0f / fmaxf((float)(end - beg), 1.f);
        float ss = 0.f;
#pragma unroll
        for (int k = 0; k < 8; ++k) {
            a[k] *= dinv;
            ss = fmaf(a[k], a[k], ss);
        }
#pragma unroll
        for (int off = 1; off <= 8; off <<= 1) ss += __shfl_xor(ss, off);
        float inv = 1.0f / fmaxf(sqrtf(ss), 1e-12f);
        if (lq == 0) {
            unsigned o0 = (unsigned)f2bf(a[0] * inv) | ((unsigned)f2bf(a[1] * inv) << 16);
            unsigned o1 = (unsigned)f2bf(a[2] * inv) | ((unsigned)f2bf(a[3] * inv) << 16);
            unsigned o2 = (unsigned)f2bf(a[4] * inv) | ((unsigned)f2bf(a[5] * inv) << 16);
            unsigned o3 = (unsigned)f2bf(a[6] * inv) | ((unsigned)f2bf(a[7] * inv) << 16);
            uint4 ov = {o0, o1, o2, o3};
            *(uint4*)&aggb[(long long)row * CH + c8] = ov;
        }
    }
}

// ---------------- MFMA dual-GEMM + leaky + add (LDS weights + dbuf A-stage) --
// 256 blocks x 1024 threads. Weights (96KB) in LDS once. A-tiles (2 strips x
// 2 planes = 16KB) double-buffered in LDS: each wave issues ONE uint4 global
// load for the NEXT strip-pair early (latency hides under MFMA), computes from
// buf[cur], ds_writes staged regs to buf[cur^1], one barrier/iter. Kills the
// r14 8x A-redundancy (410MB -> 51MB L2 traffic per hop). XOR swizzle
// chunk^(row&7) on write and read (2-way conflict = free).
__global__ __launch_bounds__(1024) void gemm_kernel(
    const unsigned short* __restrict__ xin, const unsigned short* __restrict__ aggb,
    const unsigned short* __restrict__ w1bf, const unsigned short* __restrict__ w2bf,
    const float* __restrict__ b1, const float* __restrict__ b2,
    unsigned short* __restrict__ xout, float* __restrict__ outf) {
    __shared__ __align__(16) unsigned short w1s[CH * CH];      // 32 KB
    __shared__ __align__(16) unsigned short w2s[CH * 2 * CH];  // 64 KB
    __shared__ __align__(16) unsigned char abuf[2][16384];     // 32 KB dbuf

    const int tid = threadIdx.x;
    for (int q = tid; q < 6144; q += 1024) {
        if (q < 2048) {
            int j = q >> 4, c = q & 15;
            *(bf16x8*)&w1s[j * CH + ((c ^ (j & 7)) << 3)] =
                *(const bf16x8*)&w1bf[j * CH + c * 8];
        } else {
            int qq = q - 2048;
            int j = qq >> 5, c = qq & 31;
            *(bf16x8*)&w2s[j * 2 * CH + ((c ^ (j & 7)) << 3)] =
                *(const bf16x8*)&w2bf[j * 2 * CH + c * 8];
        }
    }

    const int w = tid >> 6;
    const int h = w >> 3;   // strip-in-pair 0/1
    const int wc = w & 7;   // col group
    const int lane = tid & 63;
    const int l16 = lane & 15;
    const int lq = lane >> 4;

    // stage mapping: piece = w&7 -> (plane, row-quad); lane -> (row, chunk)
    const int plane = (w & 7) >> 2;
    const int rloc = (w & 3) * 4 + (lane >> 4);
    const int c_st = lane & 15;
    const int lds_st = h * 8192 + plane * 4096 + rloc * 256 + ((c_st ^ (rloc & 7)) << 4);
    const unsigned short* stsrc = plane ? aggb : xin;
    const long long gsrc_off = (long long)rloc * CH + c_st * 8;

    // stage strip-pair 0
    {
        int strip = blockIdx.x * 2 + h;
        if (strip < NSTRIP) {
            uint4 v = *(const uint4*)&stsrc[(long long)strip * 16 * CH + gsrc_off];
            *(uint4*)&abuf[0][lds_st] = v;
        }
    }
    __syncthreads();

    const int j = wc * 16 + l16;
    const float bb1 = b1[j];
    const float bb2 = b2[j];
    bf16x8 bW1[4], bWa[4], bWb[4];
#pragma unroll
    for (int kst = 0; kst < 4; ++kst) {
        int ca = kst * 4 + lq;
        int cb = 16 + kst * 4 + lq;
        bW1[kst] = *(const bf16x8*)&w1s[j * CH + ((ca ^ (j & 7)) << 3)];
        bWa[kst] = *(const bf16x8*)&w2s[j * 2 * CH + ((ca ^ (j & 7)) << 3)];
        bWb[kst] = *(const bf16x8*)&w2s[j * 2 * CH + ((cb ^ (j & 7)) << 3)];
    }

    int cur = 0;
    for (int it = 0; it < GEMM_NIT; ++it) {
        int strip = (blockIdx.x + it * GEMM_BLOCKS) * 2 + h;
        // early-issue next-pair loads (latency overlaps MFMA below)
        uint4 nv;
        int nstrip = (blockIdx.x + (it + 1) * GEMM_BLOCKS) * 2 + h;
        bool donext = (it + 1 < GEMM_NIT) && (nstrip < NSTRIP);
        if (donext)
            nv = *(const uint4*)&stsrc[(long long)nstrip * 16 * CH + gsrc_off];

        if (strip < NSTRIP) {
            const int row0 = strip * 16;
            const unsigned char* base = &abuf[cur][h * 8192];
            f32x4 acc1 = {0.f, 0.f, 0.f, 0.f};
            f32x4 acc2 = {0.f, 0.f, 0.f, 0.f};
#pragma unroll
            for (int kst = 0; kst < 4; ++kst) {
                int c = kst * 4 + lq;
                int off = l16 * 256 + ((c ^ (l16 & 7)) << 4);
                bf16x8 rh = *(const bf16x8*)&base[off];
                bf16x8 av = *(const bf16x8*)&base[4096 + off];
                acc1 = __builtin_amdgcn_mfma_f32_16x16x32_bf16(rh, bW1[kst], acc1, 0, 0, 0);
                acc1 = __builtin_amdgcn_mfma_f32_16x16x32_bf16(av, bW1[kst], acc1, 0, 0, 0);
                acc2 = __builtin_amdgcn_mfma_f32_16x16x32_bf16(rh, bWa[kst], acc2, 0, 0, 0);
                acc2 = __builtin_amdgcn_mfma_f32_16x16x32_bf16(av, bWb[kst], acc2, 0, 0, 0);
            }
#pragma unroll
            for (int r = 0; r < 4; ++r) {
                long long row = row0 + lq * 4 + r;
                float e1 = acc1[r] + bb1;
                e1 = e1 >= 0.f ? e1 : LEAKY * e1;
                float e2 = acc2[r] + bb2;
                e2 = e2 >= 0.f ? e2 : LEAKY * e2;
                float val = e1 + e2;
                if (outf)
                    outf[row * CH + j] = val;
                else
                    xout[row * CH + j] = f2bf(val);
            }
        }
        // publish next tile (buf[cur^1] free: its readers finished last iter)
        if (donext) *(uint4*)&abuf[cur ^ 1][lds_st] = nv;
        __syncthreads();
        cur ^= 1;
    }
}

extern "C" void kernel_launch(void* const* d_in, const int* in_sizes, int n_in,
                              void* d_out, int out_size, void* d_ws, size_t ws_size,
                              hipStream_t stream) {
    const float* emb = (const float*)d_in[0];
    const int* eidx = (const int*)d_in[1];   // int inputs arrive as int32
    const int* etype = (const int*)d_in[2];
    const float* weight = (const float*)d_in[3];
    const float* W1w = (const float*)d_in[4];
    const float* W1b = (const float*)d_in[5];
    const float* W2w = (const float*)d_in[6];
    const float* W2b = (const float*)d_in[7];

    float* out = (float*)d_out;
    float* wout = out + (size_t)N_ENT * CH;   // [32][CH]

    // workspace layout (~41.7 MB; proven fits)
    char* ws = (char*)d_ws;
    unsigned short* xh = (unsigned short*)ws;    ws += (size_t)N_ENT * CH * 2;  // 12.8 MB
    unsigned short* xh2 = (unsigned short*)ws;   ws += (size_t)N_ENT * CH * 2;  // 12.8 MB
    unsigned short* aggb = (unsigned short*)ws;  ws += (size_t)N_ENT * CH * 2;  // 12.8 MB
    unsigned short* w1bf = (unsigned short*)ws;  ws += 2 * CH * CH * 2;         // 64 KB
    unsigned short* w2bf = (unsigned short*)ws;  ws += 2 * CH * 2 * CH * 2;     // 128 KB
    float* wsf = (float*)ws;                     ws += 33 * CH * 4;             // 16.9 KB
    int* packed = (int*)ws;                      ws += (size_t)(N_EDG + 8) * 4; // 2.4 MB
    int* offs = (int*)ws;                        ws += (size_t)(N_ENT + 1) * 4;
    int* cursors = (int*)ws;                     ws += (size_t)N_ENT * 4;
    int* counts = (int*)ws;                      ws += (size_t)N_ENT * 4;
    int* bsum = (int*)ws;                        ws += 64 * 4;

    const int* head = eidx;
    const int* tail = eidx + N_EDG;

    // ---- one-time prep: counts+conversions fused, 2-kernel scan, fill ----
    hipMemsetAsync(counts, 0, N_ENT * sizeof(int), stream);
    prep_kernel<<<PREP_BLOCKS + COUNT_BLOCKS, 256, 0, stream>>>(
        emb, W1w, W2w, weight, head, xh, w1bf, w2bf, wout, wsf, counts);
    scan_block<<<NB_SCAN, 256, 0, stream>>>(counts, offs, bsum);
    add_base<<<NB_SCAN, 256, 0, stream>>>(offs, cursors, bsum);
    fill_kernel<<<1000, 256, 0, stream>>>(head, tail, etype, cursors, packed);

    // ---- 2 hops, ping-pong: xh -> (aggb) -> xh2 -> (aggb) -> d_out ----
    agg_kernel<<<AGG_BLOCKS, 512, 0, stream>>>(xh, offs, packed, wsf, aggb);
    gemm_kernel<<<GEMM_BLOCKS, 1024, 0, stream>>>(
        xh, aggb, w1bf, w2bf, W1b, W2b, xh2, (float*)nullptr);
    agg_kernel<<<AGG_BLOCKS, 512, 0, stream>>>(xh2, offs, packed, wsf, aggb);
    gemm_kernel<<<GEMM_BLOCKS, 1024, 0, stream>>>(
        xh2, aggb, w1bf + CH * CH, w2bf + CH * 2 * CH,
        W1b + CH, W2b + CH, (unsigned short*)nullptr, out);
}

// Round 17
// 162.228 us; speedup vs baseline: 1.2752x; 1.0041x over previous
//
#include <hip/hip_runtime.h>
#include <hip/hip_bf16.h>

#define N_ENT 50000
#define N_EDG 600000
#define CH 128
#define LEAKY 0.01f
#define NB_SCAN 49
#define NSTRIP 3125         // 50000 / 16
#define AGG_BLOCKS 1024     // grid-stride over 6250 row-groups of 8
#define GEMM_BLOCKS 256     // 1024 thr, 2 strips/iter
#define GEMM_NIT 7          // ceil(3125 / 512)
#define FILL_CHUNK 4800     // 600000 = 125 * 4800
#define HEADS_PER_GRP 6250  // 50000 / 8
#define PREP_BLOCKS 6351    // ceil(1,625,632 float4-units / 256)
#define COUNT_BLOCKS 2344   // ceil(600000/256)
#define SCAN_FLAG 0x40000000

typedef __attribute__((ext_vector_type(8))) short bf16x8;
typedef __attribute__((ext_vector_type(4))) float f32x4;

__device__ inline unsigned short f2bf(float x) {
    return __builtin_bit_cast(unsigned short, __float2bfloat16(x));
}
__device__ inline float bflo(unsigned u) { return __builtin_bit_cast(float, u << 16); }
__device__ inline float bfhi(unsigned u) { return __builtin_bit_cast(float, u & 0xFFFF0000u); }
__device__ inline int rfl(int x) { return __builtin_amdgcn_readfirstlane(x); }

// ---------------- prep: conversions + weight copies + degree counts ----------
__global__ __launch_bounds__(256) void prep_kernel(const float* __restrict__ emb,
                                                   const float* __restrict__ W1,
                                                   const float* __restrict__ W2,
                                                   const float* __restrict__ wsrc,
                                                   const int* __restrict__ head,
                                                   unsigned short* __restrict__ xh,
                                                   unsigned short* __restrict__ w1bf,
                                                   unsigned short* __restrict__ w2bf,
                                                   float* __restrict__ wout,
                                                   float* __restrict__ wsf,
                                                   int* __restrict__ counts) {
    if (blockIdx.x >= PREP_BLOCKS) {
        int e = (blockIdx.x - PREP_BLOCKS) * 256 + threadIdx.x;
        if (e < N_EDG) atomicAdd(&counts[head[e]], 1);
        return;
    }
    long long gid = (long long)blockIdx.x * 256 + threadIdx.x;  // float4 units
    const long long n_x = (long long)N_ENT * CH / 4;   // 1,600,000
    const long long n_w1 = 2 * CH * CH / 4;            // 8,192
    const long long n_w2 = 2 * CH * 2 * CH / 4;        // 16,384
    if (gid < n_x) {
        long long k = gid * 4;
        float4 v = *(const float4*)&emb[k];
        ushort4 o;
        o.x = f2bf(v.x); o.y = f2bf(v.y); o.z = f2bf(v.z); o.w = f2bf(v.w);
        *(ushort4*)&xh[k] = o;
    } else if (gid < n_x + n_w1) {
        long long k = (gid - n_x) * 4;
        float4 v = *(const float4*)&W1[k];
        ushort4 o;
        o.x = f2bf(v.x); o.y = f2bf(v.y); o.z = f2bf(v.z); o.w = f2bf(v.w);
        *(ushort4*)&w1bf[k] = o;
    } else if (gid < n_x + n_w1 + n_w2) {
        long long k = (gid - n_x - n_w1) * 4;
        float4 v = *(const float4*)&W2[k];
        ushort4 o;
        o.x = f2bf(v.x); o.y = f2bf(v.y); o.z = f2bf(v.z); o.w = f2bf(v.w);
        *(ushort4*)&w2bf[k] = o;
    } else {
        long long k = gid - n_x - n_w1 - n_w2;  // float4 units
        if (k < 1024) {
            float4 v = *(const float4*)&wsrc[k * 4];
            *(float4*)&wout[k * 4] = v;
            *(float4*)&wsf[k * 4] = v;
        } else if (k < 1056) {  // zero row 32 of wsf (tail-edge masking)
            float4 z = {0.f, 0.f, 0.f, 0.f};
            *(float4*)&wsf[k * 4] = z;
        }
    }
}

// ---------------- CSR scan: single dispatch, decoupled lookback --------------
// 49 blocks (all trivially co-resident on 256 CUs -> spin is deadlock-free).
// Each block scans its 1024-entity chunk, publishes total|FLAG via
// device-scope atomic, wave 0 spin-reads predecessors. bsum is memset to 0
// with counts each launch (clears flags across graph replays).
__global__ __launch_bounds__(256) void scan_fused(const int* __restrict__ counts,
                                                  int* __restrict__ offs,
                                                  int* __restrict__ cursors,
                                                  int* __restrict__ bsum) {
    __shared__ int s[256];
    __shared__ int base_s;
    int t = threadIdx.x;
    int base = blockIdx.x * 1024 + t * 4;
    int v[4];
#pragma unroll
    for (int i = 0; i < 4; ++i) {
        int idx = base + i;
        v[i] = (idx < N_ENT) ? counts[idx] : 0;
    }
    int tot = v[0] + v[1] + v[2] + v[3];
    s[t] = tot;
    for (int off = 1; off < 256; off <<= 1) {
        __syncthreads();
        int x = (t >= off) ? s[t - off] : 0;
        __syncthreads();
        s[t] += x;
    }
    if (t == 255) atomicExch(&bsum[blockIdx.x], s[255] | SCAN_FLAG);
    if (t < 64) {
        int acc = 0;
        if (t < (int)blockIdx.x) {  // <= 48 predecessors
            int val;
            do {
                val = atomicAdd(&bsum[t], 0);
            } while ((val & SCAN_FLAG) == 0);
            acc = val & (SCAN_FLAG - 1);
        }
#pragma unroll
        for (int off = 1; off < 64; off <<= 1) acc += __shfl_xor(acc, off);
        if (t == 0) base_s = acc;
    }
    __syncthreads();
    int run = s[t] - tot + base_s;  // exclusive prefix + block base
#pragma unroll
    for (int i = 0; i < 4; ++i) {
        int idx = base + i;
        if (idx < N_ENT) {
            offs[idx] = run;
            cursors[idx] = run;
        }
        run += v[i];
    }
    if (blockIdx.x == 0 && t == 0) offs[N_ENT] = N_EDG;
}

// ---------------- CSR fill: packed edge payloads (XCD-partitioned) -----------
__global__ __launch_bounds__(256) void fill_kernel(const int* __restrict__ head,
                                                   const int* __restrict__ tail,
                                                   const int* __restrict__ etype,
                                                   int* __restrict__ cursors,
                                                   int* __restrict__ packed) {
    int g = blockIdx.x & 7;
    int c = blockIdx.x >> 3;  // 0..124
    int hlo = g * HEADS_PER_GRP;
    int hhi = hlo + HEADS_PER_GRP;
    int base = c * FILL_CHUNK;
    for (int t = threadIdx.x; t < FILL_CHUNK; t += 256) {
        int e = base + t;
        int h = head[e];
        if (h >= hlo && h < hhi) {
            int pos = atomicAdd(&cursors[h], 1);
            packed[pos] = tail[e] | (etype[e] << 20);
        }
    }
}

// ---------------- aggregate + mean + L2-normalize (bf16 quad-gather) ---------
// One wave per row; lane = (lq = edge slot, l16 = 16B chunk); one dwordx4
// gathers 4 edges' rows; 2-quad unroll = 8 edges in flight. Tail edges
// masked via zero weight row 32. LDS stride 132 = bank-spread.
__global__ __launch_bounds__(512) void agg_kernel(
    const unsigned short* __restrict__ xin, const int* __restrict__ offs,
    const int* __restrict__ packed, const float* __restrict__ wsf,
    unsigned short* __restrict__ aggb) {
    __shared__ float ws_[33 * 132];  // 17.4 KB
    int tid = threadIdx.x;
    for (int q = tid; q < 1056; q += 512) {  // 33 rows x 32 float4
        float4 v = *(const float4*)&wsf[q * 4];
        *(float4*)&ws_[(q >> 5) * 132 + (q & 31) * 4] = v;
    }
    __syncthreads();

    const int w = tid >> 6;
    const int lane = tid & 63;
    const int l16 = lane & 15;
    const int lq = lane >> 4;
    const int c8 = l16 * 8;

    for (int rb = blockIdx.x; rb < 6250; rb += AGG_BLOCKS) {
        const int row = rb * 8 + w;
        const int beg = rfl(offs[row]);
        const int end = rfl(offs[row + 1]);

        float a[8] = {0.f, 0.f, 0.f, 0.f, 0.f, 0.f, 0.f, 0.f};
        float b[8] = {0.f, 0.f, 0.f, 0.f, 0.f, 0.f, 0.f, 0.f};

        for (int i = beg; i < end; i += 8) {
            int pa0 = rfl(packed[i]);
            int pa1 = rfl(packed[i + 1]);
            int pa2 = rfl(packed[i + 2]);
            int pa3 = rfl(packed[i + 3]);
            int pb0 = rfl(packed[i + 4]);
            int pb1 = rfl(packed[i + 5]);
            int pb2 = rfl(packed[i + 6]);
            int pb3 = rfl(packed[i + 7]);
            int pA = lq == 0 ? pa0 : lq == 1 ? pa1 : lq == 2 ? pa2 : pa3;
            int pB = lq == 0 ? pb0 : lq == 1 ? pb1 : lq == 2 ? pb2 : pb3;
            bool okA = (i + lq) < end;
            bool okB = (i + 4 + lq) < end;
            int tA = (okA ? pA : pa0) & 0xFFFFF;
            int tB = (okB ? pB : pa0) & 0xFFFFF;
            int rA = okA ? (pA >> 20) : 32;
            int rB = okB ? (pB >> 20) : 32;
            uint4 vA = *(const uint4*)&xin[(long long)tA * CH + c8];
            uint4 vB = *(const uint4*)&xin[(long long)tB * CH + c8];
            float wvA[8], wvB[8];
            *(float4*)&wvA[0] = *(const float4*)&ws_[rA * 132 + c8];
            *(float4*)&wvA[4] = *(const float4*)&ws_[rA * 132 + c8 + 4];
            *(float4*)&wvB[0] = *(const float4*)&ws_[rB * 132 + c8];
            *(float4*)&wvB[4] = *(const float4*)&ws_[rB * 132 + c8 + 4];
            unsigned ua[4] = {vA.x, vA.y, vA.z, vA.w};
            unsigned ub[4] = {vB.x, vB.y, vB.z, vB.w};
#pragma unroll
            for (int k = 0; k < 4; ++k) {
                a[2 * k] = fmaf(bflo(ua[k]), wvA[2 * k], a[2 * k]);
                a[2 * k + 1] = fmaf(bfhi(ua[k]), wvA[2 * k + 1], a[2 * k + 1]);
                b[2 * k] = fmaf(bflo(ub[k]), wvB[2 * k], b[2 * k]);
                b[2 * k + 1] = fmaf(bfhi(ub[k]), wvB[2 * k + 1], b[2 * k + 1]);
            }
        }

#pragma unroll
        for (int k = 0; k < 8; ++k) {
            a[k] += b[k];
            a[k] += __shfl_xor(a[k], 16);
            a[k] += __shfl_xor(a[k], 32);
        }
        float dinv = 1.0f / fmaxf((float)(end - beg), 1.f);
        float ss = 0.f;
#pragma unroll
        for (int k = 0; k < 8; ++k) {
            a[k] *= dinv;
            ss = fmaf(a[k], a[k], ss);
        }
#pragma unroll
        for (int off = 1; off <= 8; off <<= 1) ss += __shfl_xor(ss, off);
        float inv = 1.0f / fmaxf(sqrtf(ss), 1e-12f);
        if (lq == 0) {
            unsigned o0 = (unsigned)f2bf(a[0] * inv) | ((unsigned)f2bf(a[1] * inv) << 16);
            unsigned o1 = (unsigned)f2bf(a[2] * inv) | ((unsigned)f2bf(a[3] * inv) << 16);
            unsigned o2 = (unsigned)f2bf(a[4] * inv) | ((unsigned)f2bf(a[5] * inv) << 16);
            unsigned o3 = (unsigned)f2bf(a[6] * inv) | ((unsigned)f2bf(a[7] * inv) << 16);
            uint4 ov = {o0, o1, o2, o3};
            *(uint4*)&aggb[(long long)row * CH + c8] = ov;
        }
    }
}

// ---------------- MFMA dual-GEMM + leaky + add (LDS weights + dbuf A-stage) --
// r16-proven. 256 blocks x 1024 threads. Weights (96KB) in LDS once; A-tiles
// double-buffered (early global load overlaps MFMA, ds_write after compute,
// one barrier/iter). XOR swizzle chunk^(row&7) both sides.
__global__ __launch_bounds__(1024) void gemm_kernel(
    const unsigned short* __restrict__ xin, const unsigned short* __restrict__ aggb,
    const unsigned short* __restrict__ w1bf, const unsigned short* __restrict__ w2bf,
    const float* __restrict__ b1, const float* __restrict__ b2,
    unsigned short* __restrict__ xout, float* __restrict__ outf) {
    __shared__ __align__(16) unsigned short w1s[CH * CH];      // 32 KB
    __shared__ __align__(16) unsigned short w2s[CH * 2 * CH];  // 64 KB
    __shared__ __align__(16) unsigned char abuf[2][16384];     // 32 KB dbuf

    const int tid = threadIdx.x;
    for (int q = tid; q < 6144; q += 1024) {
        if (q < 2048) {
            int j = q >> 4, c = q & 15;
            *(bf16x8*)&w1s[j * CH + ((c ^ (j & 7)) << 3)] =
                *(const bf16x8*)&w1bf[j * CH + c * 8];
        } else {
            int qq = q - 2048;
            int j = qq >> 5, c = qq & 31;
            *(bf16x8*)&w2s[j * 2 * CH + ((c ^ (j & 7)) << 3)] =
                *(const bf16x8*)&w2bf[j * 2 * CH + c * 8];
        }
    }

    const int w = tid >> 6;
    const int h = w >> 3;   // strip-in-pair 0/1
    const int wc = w & 7;   // col group
    const int lane = tid & 63;
    const int l16 = lane & 15;
    const int lq = lane >> 4;

    const int plane = (w & 7) >> 2;
    const int rloc = (w & 3) * 4 + (lane >> 4);
    const int c_st = lane & 15;
    const int lds_st = h * 8192 + plane * 4096 + rloc * 256 + ((c_st ^ (rloc & 7)) << 4);
    const unsigned short* stsrc = plane ? aggb : xin;
    const long long gsrc_off = (long long)rloc * CH + c_st * 8;

    {
        int strip = blockIdx.x * 2 + h;
        if (strip < NSTRIP) {
            uint4 v = *(const uint4*)&stsrc[(long long)strip * 16 * CH + gsrc_off];
            *(uint4*)&abuf[0][lds_st] = v;
        }
    }
    __syncthreads();

    const int j = wc * 16 + l16;
    const float bb1 = b1[j];
    const float bb2 = b2[j];
    bf16x8 bW1[4], bWa[4], bWb[4];
#pragma unroll
    for (int kst = 0; kst < 4; ++kst) {
        int ca = kst * 4 + lq;
        int cb = 16 + kst * 4 + lq;
        bW1[kst] = *(const bf16x8*)&w1s[j * CH + ((ca ^ (j & 7)) << 3)];
        bWa[kst] = *(const bf16x8*)&w2s[j * 2 * CH + ((ca ^ (j & 7)) << 3)];
        bWb[kst] = *(const bf16x8*)&w2s[j * 2 * CH + ((cb ^ (j & 7)) << 3)];
    }

    int cur = 0;
    for (int it = 0; it < GEMM_NIT; ++it) {
        int strip = (blockIdx.x + it * GEMM_BLOCKS) * 2 + h;
        uint4 nv;
        int nstrip = (blockIdx.x + (it + 1) * GEMM_BLOCKS) * 2 + h;
        bool donext = (it + 1 < GEMM_NIT) && (nstrip < NSTRIP);
        if (donext)
            nv = *(const uint4*)&stsrc[(long long)nstrip * 16 * CH + gsrc_off];

        if (strip < NSTRIP) {
            const int row0 = strip * 16;
            const unsigned char* base = &abuf[cur][h * 8192];
            f32x4 acc1 = {0.f, 0.f, 0.f, 0.f};
            f32x4 acc2 = {0.f, 0.f, 0.f, 0.f};
#pragma unroll
            for (int kst = 0; kst < 4; ++kst) {
                int c = kst * 4 + lq;
                int off = l16 * 256 + ((c ^ (l16 & 7)) << 4);
                bf16x8 rh = *(const bf16x8*)&base[off];
                bf16x8 av = *(const bf16x8*)&base[4096 + off];
                acc1 = __builtin_amdgcn_mfma_f32_16x16x32_bf16(rh, bW1[kst], acc1, 0, 0, 0);
                acc1 = __builtin_amdgcn_mfma_f32_16x16x32_bf16(av, bW1[kst], acc1, 0, 0, 0);
                acc2 = __builtin_amdgcn_mfma_f32_16x16x32_bf16(rh, bWa[kst], acc2, 0, 0, 0);
                acc2 = __builtin_amdgcn_mfma_f32_16x16x32_bf16(av, bWb[kst], acc2, 0, 0, 0);
            }
#pragma unroll
            for (int r = 0; r < 4; ++r) {
                long long row = row0 + lq * 4 + r;
                float e1 = acc1[r] + bb1;
                e1 = e1 >= 0.f ? e1 : LEAKY * e1;
                float e2 = acc2[r] + bb2;
                e2 = e2 >= 0.f ? e2 : LEAKY * e2;
                float val = e1 + e2;
                if (outf)
                    outf[row * CH + j] = val;
                else
                    xout[row * CH + j] = f2bf(val);
            }
        }
        if (donext) *(uint4*)&abuf[cur ^ 1][lds_st] = nv;
        __syncthreads();
        cur ^= 1;
    }
}

extern "C" void kernel_launch(void* const* d_in, const int* in_sizes, int n_in,
                              void* d_out, int out_size, void* d_ws, size_t ws_size,
                              hipStream_t stream) {
    const float* emb = (const float*)d_in[0];
    const int* eidx = (const int*)d_in[1];   // int inputs arrive as int32
    const int* etype = (const int*)d_in[2];
    const float* weight = (const float*)d_in[3];
    const float* W1w = (const float*)d_in[4];
    const float* W1b = (const float*)d_in[5];
    const float* W2w = (const float*)d_in[6];
    const float* W2b = (const float*)d_in[7];

    float* out = (float*)d_out;
    float* wout = out + (size_t)N_ENT * CH;   // [32][CH]

    // workspace layout (~41.7 MB; proven fits). counts+bsum contiguous so one
    // memset clears both (bsum flags must be zeroed each launch).
    char* ws = (char*)d_ws;
    unsigned short* xh = (unsigned short*)ws;    ws += (size_t)N_ENT * CH * 2;  // 12.8 MB
    unsigned short* xh2 = (unsigned short*)ws;   ws += (size_t)N_ENT * CH * 2;  // 12.8 MB
    unsigned short* aggb = (unsigned short*)ws;  ws += (size_t)N_ENT * CH * 2;  // 12.8 MB
    unsigned short* w1bf = (unsigned short*)ws;  ws += 2 * CH * CH * 2;         // 64 KB
    unsigned short* w2bf = (unsigned short*)ws;  ws += 2 * CH * 2 * CH * 2;     // 128 KB
    float* wsf = (float*)ws;                     ws += 33 * CH * 4;             // 16.9 KB
    int* packed = (int*)ws;                      ws += (size_t)(N_EDG + 8) * 4; // 2.4 MB
    int* offs = (int*)ws;                        ws += (size_t)(N_ENT + 1) * 4;
    int* cursors = (int*)ws;                     ws += (size_t)N_ENT * 4;
    int* counts = (int*)ws;                      ws += (size_t)N_ENT * 4;
    int* bsum = (int*)ws;                        ws += 64 * 4;

    const int* head = eidx;
    const int* tail = eidx + N_EDG;

    // ---- one-time prep: counts+conversions fused, 1-dispatch scan, fill ----
    hipMemsetAsync(counts, 0, (N_ENT + 64) * sizeof(int), stream);
    prep_kernel<<<PREP_BLOCKS + COUNT_BLOCKS, 256, 0, stream>>>(
        emb, W1w, W2w, weight, head, xh, w1bf, w2bf, wout, wsf, counts);
    scan_fused<<<NB_SCAN, 256, 0, stream>>>(counts, offs, cursors, bsum);
    fill_kernel<<<1000, 256, 0, stream>>>(head, tail, etype, cursors, packed);

    // ---- 2 hops, ping-pong: xh -> (aggb) -> xh2 -> (aggb) -> d_out ----
    agg_kernel<<<AGG_BLOCKS, 512, 0, stream>>>(xh, offs, packed, wsf, aggb);
    gemm_kernel<<<GEMM_BLOCKS, 1024, 0, stream>>>(
        xh, aggb, w1bf, w2bf, W1b, W2b, xh2, (float*)nullptr);
    agg_kernel<<<AGG_BLOCKS, 512, 0, stream>>>(xh2, offs, packed, wsf, aggb);
    gemm_kernel<<<GEMM_BLOCKS, 1024, 0, stream>>>(
        xh2, aggb, w1bf + CH * CH, w2bf + CH * 2 * CH,
        W1b + CH, W2b + CH, (unsigned short*)nullptr, out);
}